// Round 1
// baseline (4689.270 us; speedup 1.0000x reference)
//
#include <hip/hip_runtime.h>

// OscillatoryDPLRSSM — chunked parallel scan, fp32 baseline.
//
// Algorithm:
//   E = (dt/2) * (diag(lam) + P Q^T)            (complex 64x64, ||E|| ~ 5e-3)
//   Minv ~= (I+E)(I+E^2)                        (Neumann, error ~E^4 ~ 1e-9)
//   A_d = 2*Minv - I ; B_d = 0.05*(A_d+I)*B
//   bu[b,t,:] = [Re(B_d u); Im(B_d u)]          (GEMM, stored in d_out as scratch)
//   chunked scan (L=64, C=128 chunks):
//     pass1: local scans from 0 -> chunk end states e[b,c]
//     phase2: s[b,c] = A_d^64 s[b,c-1] + e[b,c] (sequential over 128 chunks only)
//     pass3: local scans seeded with sIn=s[b,c-1], emit Re(x) -> xr
//   y = xr @ C^T + u @ D^T
//
// Workspace layout (floats):
#define OFF_E      0L          // float2[64*64]  -> 8192 floats
#define OFF_E2     8192L
#define OFF_AD     16384L
#define OFF_P0     24576L
#define OFF_P1     32768L
#define OFF_AHAT   40960L      // 128*128
#define OFF_ALHAT  57344L
#define OFF_WBU    73728L
#define OFF_EST    90112L      // 4096*128
#define OFF_SIN    614400L     // 4096*128
#define OFF_XR     1138688L    // 262144*64
// total = 17,915,904 floats = 71.7 MB

// ---------------- setup kernels ----------------

__global__ void build_E(const float* __restrict__ lw, const float* __restrict__ zl,
                        const float* __restrict__ P, const float* __restrict__ Q,
                        float2* __restrict__ E)
{
    int idx = blockIdx.x * 256 + threadIdx.x;   // 4096 elements
    if (idx >= 4096) return;
    int i = idx >> 6, j = idx & 63;
    float pq = 0.f;
    #pragma unroll
    for (int r = 0; r < 4; ++r) pq += P[i*4+r] * Q[j*4+r];
    float ex = pq, ey = 0.f;
    if (i == j) {
        float om = expf(lw[i]);
        float ze = 1.f / (1.f + expf(-zl[i]));
        ex += -ze * om;
        ey  = om * sqrtf(fmaxf(1.f - ze*ze, 1e-8f));
    }
    E[idx] = make_float2(0.005f * ex, 0.005f * ey);
}

// Co = (A + aI*I)(B + bI*I); post: Co = 2*Co - I
__global__ __launch_bounds__(256) void cgemm64(const float2* __restrict__ A,
                                               const float2* __restrict__ B,
                                               float2* __restrict__ Co,
                                               int aI, int bI, int post)
{
    int g = blockIdx.x * 256 + threadIdx.x;     // grid 4 -> g in [0,1024)
    #pragma unroll
    for (int q = 0; q < 4; ++q) {
        int idx = g + q * 1024;
        int i = idx >> 6, j = idx & 63;
        float accx = 0.f, accy = 0.f;
        for (int k = 0; k < 64; ++k) {
            float2 a = A[i*64 + k];
            if (aI && k == i) a.x += 1.f;
            float2 b = B[k*64 + j];
            if (bI && k == j) b.x += 1.f;
            accx += a.x*b.x - a.y*b.y;
            accy += a.x*b.y + a.y*b.x;
        }
        if (post) { accx = 2.f*accx - (i == j ? 1.f : 0.f); accy = 2.f*accy; }
        Co[idx] = make_float2(accx, accy);
    }
}

// Wbu (128x128): rows 0..63 = Re(B_d), rows 64..127 = Im(B_d); B_d = 0.05*(A_d+I)*B
__global__ __launch_bounds__(256) void k_bd(const float2* __restrict__ Ad,
                                            const float* __restrict__ Bm,
                                            float* __restrict__ Wbu)
{
    int idx = blockIdx.x * 256 + threadIdx.x;   // 8192
    int n = idx >> 7, i = idx & 127;
    float ar = 0.f, ai = 0.f;
    for (int m = 0; m < 64; ++m) {
        float2 a = Ad[n*64 + m];
        float b = Bm[m*128 + i];
        ar += a.x * b; ai += a.y * b;
    }
    ar += Bm[n*128 + i];                         // +I*B
    Wbu[n*128 + i]      = 0.05f * ar;
    Wbu[(64+n)*128 + i] = 0.05f * ai;
}

// real embedding [[Ar,-Ai],[Ai,Ar]] for A_d and A_d^64
__global__ void k_embed(const float2* __restrict__ Ad, const float2* __restrict__ M64,
                        float* __restrict__ Ahat, float* __restrict__ ALhat)
{
    int idx = blockIdx.x * 256 + threadIdx.x;   // 32768
    int sel = idx >> 14;
    int rem = idx & 16383;
    int i = rem >> 7, j = rem & 127;
    const float2* S = sel ? M64 : Ad;
    float2 v = S[(i & 63)*64 + (j & 63)];
    float o = (i < 64) ? ((j < 64) ? v.x : -v.y)
                       : ((j < 64) ? v.y :  v.x);
    (sel ? ALhat : Ahat)[i*128 + j] = o;
}

// ---------------- big GEMM: Y[M][128] = X1 @ W1^T (+ X2 @ W2^T) ----------------
// X1: [M][K1], W1: [128][K1]. 64x64 tile per wg, 4x4 micro-tile, LDS k-halves.
__global__ __launch_bounds__(256) void gemm_dual(
    const float* __restrict__ X1, int K1, const float* __restrict__ W1,
    const float* __restrict__ X2, int K2v, const float* __restrict__ W2,
    float* __restrict__ Y)
{
    __shared__ float xs_s[64][68];
    __shared__ float ws_s[64][68];
    int t = threadIdx.x;
    int tx = t & 15, ty = t >> 4;
    long row0 = (long)blockIdx.x * 64;
    int  col0 = blockIdx.y * 64;
    float acc[4][4] = {};
    for (int op = 0; op < 2; ++op) {
        const float* X = op ? X2 : X1;
        const float* W = op ? W2 : W1;
        int K = op ? K2v : K1;
        if (X == nullptr) continue;
        for (int kh = 0; kh < K; kh += 64) {
            __syncthreads();
            for (int m = t; m < 64*16; m += 256) {
                int r = m >> 4, cq = m & 15;
                *(float4*)&xs_s[r][cq*4] = *(const float4*)&X[(row0 + r)*K + kh + cq*4];
                *(float4*)&ws_s[r][cq*4] = *(const float4*)&W[(long)(col0 + r)*K + kh + cq*4];
            }
            __syncthreads();
            #pragma unroll
            for (int kq = 0; kq < 16; ++kq) {
                float4 xv[4], wv[4];
                #pragma unroll
                for (int r = 0; r < 4; ++r) xv[r] = *(const float4*)&xs_s[ty + 16*r][kq*4];
                #pragma unroll
                for (int j = 0; j < 4; ++j) wv[j] = *(const float4*)&ws_s[tx + 16*j][kq*4];
                #pragma unroll
                for (int r = 0; r < 4; ++r)
                    #pragma unroll
                    for (int j = 0; j < 4; ++j)
                        acc[r][j] += xv[r].x*wv[j].x + xv[r].y*wv[j].y
                                   + xv[r].z*wv[j].z + xv[r].w*wv[j].w;
            }
        }
    }
    #pragma unroll
    for (int r = 0; r < 4; ++r)
        #pragma unroll
        for (int j = 0; j < 4; ++j)
            Y[(row0 + ty + 16*r)*128 + col0 + tx + 16*j] = acc[r][j];
}

// ---------------- chunked scan passes ----------------
// rows are (b*128 + c), b in [0,32), c chunk in [0,128). 8 rows per wg.
// pass==1: x init 0, write chunk-end to eOut.  pass==3: x init sIn, write Re(x) to xrOut.
__global__ __launch_bounds__(256, 2) void scan_pass(
    const float* __restrict__ Ahat, const float* __restrict__ bu,
    const float* __restrict__ sIn, float* __restrict__ eOut,
    float* __restrict__ xrOut, int pass)
{
    __shared__ float xs[2][8][132];
    int t = threadIdx.x;
    int i = t & 127, rg = t >> 7, rg4 = rg * 4;
    float a[128];
    #pragma unroll
    for (int kq = 0; kq < 32; ++kq) {
        float4 v = *(const float4*)&Ahat[i*128 + kq*4];
        a[kq*4+0] = v.x; a[kq*4+1] = v.y; a[kq*4+2] = v.z; a[kq*4+3] = v.w;
    }
    int rowBase = blockIdx.x * 8 + rg4;
    long buOff[4];
    #pragma unroll
    for (int r = 0; r < 4; ++r) {
        int row = rowBase + r;
        long b = row >> 7, c = row & 127;
        buOff[r] = (b * 8192 + c * 64) * 128;
        float v0 = (pass == 3) ? sIn[(long)row*128 + i] : 0.f;
        xs[0][rg4 + r][i] = v0;
    }
    __syncthreads();
    int cur = 0;
    for (int tau = 0; tau < 64; ++tau) {
        float breg[4];
        #pragma unroll
        for (int r = 0; r < 4; ++r) breg[r] = bu[buOff[r] + (long)tau*128 + i];
        float acc[4] = {0.f, 0.f, 0.f, 0.f};
        #pragma unroll
        for (int kq = 0; kq < 32; ++kq) {
            float a0 = a[kq*4], a1 = a[kq*4+1], a2 = a[kq*4+2], a3 = a[kq*4+3];
            #pragma unroll
            for (int r = 0; r < 4; ++r) {
                float4 xv = *(const float4*)&xs[cur][rg4 + r][kq*4];
                acc[r] += a0*xv.x + a1*xv.y + a2*xv.z + a3*xv.w;
            }
        }
        #pragma unroll
        for (int r = 0; r < 4; ++r) {
            float xn = acc[r] + breg[r];
            xs[cur ^ 1][rg4 + r][i] = xn;
            if (pass == 3 && i < 64) xrOut[(buOff[r] >> 1) + (long)tau*64 + i] = xn;
        }
        __syncthreads();
        cur ^= 1;
    }
    if (pass == 1) {
        #pragma unroll
        for (int r = 0; r < 4; ++r)
            eOut[(long)(rowBase + r)*128 + i] = xs[cur][rg4 + r][i];
    }
}

// phase 2: per batch b, s[c] = ALhat s[c-1] + e[c]; store incoming carry sOut[c] = s[c-1]
__global__ __launch_bounds__(128) void phase2(const float* __restrict__ ALhat,
                                              const float* __restrict__ eIn,
                                              float* __restrict__ sOut)
{
    __shared__ float s_s[132];
    int i = threadIdx.x;
    int b = blockIdx.x;
    float a[128];
    #pragma unroll
    for (int kq = 0; kq < 32; ++kq) {
        float4 v = *(const float4*)&ALhat[i*128 + kq*4];
        a[kq*4+0] = v.x; a[kq*4+1] = v.y; a[kq*4+2] = v.z; a[kq*4+3] = v.w;
    }
    s_s[i] = 0.f;
    __syncthreads();
    for (int c = 0; c < 128; ++c) {
        long row = (long)b*128 + c;
        float e = eIn[row*128 + i];
        sOut[row*128 + i] = s_s[i];          // incoming carry s[c-1]
        float acc = 0.f;
        #pragma unroll
        for (int kq = 0; kq < 32; ++kq) {
            float4 sv = *(const float4*)&s_s[kq*4];
            acc += a[kq*4+0]*sv.x + a[kq*4+1]*sv.y + a[kq*4+2]*sv.z + a[kq*4+3]*sv.w;
        }
        __syncthreads();
        s_s[i] = acc + e;
        __syncthreads();
    }
}

// ---------------- launch ----------------

extern "C" void kernel_launch(void* const* d_in, const int* in_sizes, int n_in,
                              void* d_out, int out_size, void* d_ws, size_t ws_size,
                              hipStream_t stream) {
    const float* u  = (const float*)d_in[0];
    const float* lw = (const float*)d_in[1];
    const float* zl = (const float*)d_in[2];
    const float* P  = (const float*)d_in[3];
    const float* Q  = (const float*)d_in[4];
    const float* Bm = (const float*)d_in[5];
    const float* Cm = (const float*)d_in[6];
    const float* Dm = (const float*)d_in[7];
    float* y = (float*)d_out;
    float* w = (float*)d_ws;

    float2* E   = (float2*)(w + OFF_E);
    float2* E2  = (float2*)(w + OFF_E2);
    float2* AD  = (float2*)(w + OFF_AD);
    float2* P0  = (float2*)(w + OFF_P0);
    float2* P1  = (float2*)(w + OFF_P1);
    float*  Ahat  = w + OFF_AHAT;
    float*  ALhat = w + OFF_ALHAT;
    float*  Wbu   = w + OFF_WBU;
    float*  Est   = w + OFF_EST;
    float*  SIn   = w + OFF_SIN;
    float*  XR    = w + OFF_XR;

    // setup
    build_E<<<16, 256, 0, stream>>>(lw, zl, P, Q, E);
    cgemm64<<<4, 256, 0, stream>>>(E, E, E2, 0, 0, 0);        // E^2
    cgemm64<<<4, 256, 0, stream>>>(E, E2, AD, 1, 1, 1);       // A_d = 2(I+E)(I+E^2) - I
    k_bd<<<32, 256, 0, stream>>>(AD, Bm, Wbu);
    cgemm64<<<4, 256, 0, stream>>>(AD, AD, P0, 0, 0, 0);      // A^2
    cgemm64<<<4, 256, 0, stream>>>(P0, P0, P1, 0, 0, 0);      // A^4
    cgemm64<<<4, 256, 0, stream>>>(P1, P1, P0, 0, 0, 0);      // A^8
    cgemm64<<<4, 256, 0, stream>>>(P0, P0, P1, 0, 0, 0);      // A^16
    cgemm64<<<4, 256, 0, stream>>>(P1, P1, P0, 0, 0, 0);      // A^32
    cgemm64<<<4, 256, 0, stream>>>(P0, P0, P1, 0, 0, 0);      // A^64
    k_embed<<<128, 256, 0, stream>>>(AD, P1, Ahat, ALhat);

    // bu = u @ Wbu^T  -> stored in d_out (scratch reuse)
    gemm_dual<<<dim3(4096, 2), 256, 0, stream>>>(u, 128, Wbu, nullptr, 0, nullptr, y);

    // chunked scan
    scan_pass<<<512, 256, 0, stream>>>(Ahat, y, nullptr, Est, nullptr, 1);
    phase2<<<32, 128, 0, stream>>>(ALhat, Est, SIn);
    scan_pass<<<512, 256, 0, stream>>>(Ahat, y, SIn, nullptr, XR, 3);

    // y = xr @ C^T + u @ D^T  (overwrites d_out)
    gemm_dual<<<dim3(4096, 2), 256, 0, stream>>>(XR, 64, Cm, u, 128, Dm, y);
}

// Round 2
// 1644.737 us; speedup vs baseline: 2.8511x; 2.8511x over previous
//
#include <hip/hip_runtime.h>

// OscillatoryDPLRSSM — chunked parallel scan, fp32, spill-free scan (R2).
//
// Algorithm:
//   E = (dt/2) * (diag(lam) + P Q^T)            (complex 64x64, ||E|| ~ 5e-3)
//   Minv ~= (I+E)(I+E^2)                        (Neumann, error ~E^4 ~ 1e-9)
//   A_d = 2*Minv - I ; B_d = 0.05*(A_d+I)*B
//   bu[b,t,:] = [Re(B_d u); Im(B_d u)]          (GEMM, stored in d_out as scratch)
//   chunked scan (L=64, C=128 chunks):
//     pass1: local scans from 0 -> chunk end states e[b,c]
//     phase2: s[b,c] = A_d^64 s[b,c-1] + e[b,c] (sequential over 128 chunks only)
//     pass3: local scans seeded with sIn=s[b,c-1], emit Re(x) -> xr
//   y = xr @ C^T + u @ D^T
//
// Workspace layout (floats):
#define OFF_E      0L          // float2[64*64]  -> 8192 floats
#define OFF_E2     8192L
#define OFF_AD     16384L
#define OFF_P0     24576L
#define OFF_P1     32768L
#define OFF_AHAT   40960L      // 128*128
#define OFF_ALHAT  57344L
#define OFF_WBU    73728L
#define OFF_EST    90112L      // 4096*128
#define OFF_SIN    614400L     // 4096*128
#define OFF_XR     1138688L    // 262144*64
// total = 17,915,904 floats = 71.7 MB

// ---------------- setup kernels ----------------

__global__ void build_E(const float* __restrict__ lw, const float* __restrict__ zl,
                        const float* __restrict__ P, const float* __restrict__ Q,
                        float2* __restrict__ E)
{
    int idx = blockIdx.x * 256 + threadIdx.x;   // 4096 elements
    if (idx >= 4096) return;
    int i = idx >> 6, j = idx & 63;
    float pq = 0.f;
    #pragma unroll
    for (int r = 0; r < 4; ++r) pq += P[i*4+r] * Q[j*4+r];
    float ex = pq, ey = 0.f;
    if (i == j) {
        float om = expf(lw[i]);
        float ze = 1.f / (1.f + expf(-zl[i]));
        ex += -ze * om;
        ey  = om * sqrtf(fmaxf(1.f - ze*ze, 1e-8f));
    }
    E[idx] = make_float2(0.005f * ex, 0.005f * ey);
}

// Co = (A + aI*I)(B + bI*I); post: Co = 2*Co - I
__global__ __launch_bounds__(256) void cgemm64(const float2* __restrict__ A,
                                               const float2* __restrict__ B,
                                               float2* __restrict__ Co,
                                               int aI, int bI, int post)
{
    int g = blockIdx.x * 256 + threadIdx.x;     // grid 4 -> g in [0,1024)
    #pragma unroll
    for (int q = 0; q < 4; ++q) {
        int idx = g + q * 1024;
        int i = idx >> 6, j = idx & 63;
        float accx = 0.f, accy = 0.f;
        for (int k = 0; k < 64; ++k) {
            float2 a = A[i*64 + k];
            if (aI && k == i) a.x += 1.f;
            float2 b = B[k*64 + j];
            if (bI && k == j) b.x += 1.f;
            accx += a.x*b.x - a.y*b.y;
            accy += a.x*b.y + a.y*b.x;
        }
        if (post) { accx = 2.f*accx - (i == j ? 1.f : 0.f); accy = 2.f*accy; }
        Co[idx] = make_float2(accx, accy);
    }
}

// Wbu (128x128): rows 0..63 = Re(B_d), rows 64..127 = Im(B_d); B_d = 0.05*(A_d+I)*B
__global__ __launch_bounds__(256) void k_bd(const float2* __restrict__ Ad,
                                            const float* __restrict__ Bm,
                                            float* __restrict__ Wbu)
{
    int idx = blockIdx.x * 256 + threadIdx.x;   // 8192
    int n = idx >> 7, i = idx & 127;
    float ar = 0.f, ai = 0.f;
    for (int m = 0; m < 64; ++m) {
        float2 a = Ad[n*64 + m];
        float b = Bm[m*128 + i];
        ar += a.x * b; ai += a.y * b;
    }
    ar += Bm[n*128 + i];                         // +I*B
    Wbu[n*128 + i]      = 0.05f * ar;
    Wbu[(64+n)*128 + i] = 0.05f * ai;
}

// real embedding [[Ar,-Ai],[Ai,Ar]] for A_d and A_d^64
__global__ void k_embed(const float2* __restrict__ Ad, const float2* __restrict__ M64,
                        float* __restrict__ Ahat, float* __restrict__ ALhat)
{
    int idx = blockIdx.x * 256 + threadIdx.x;   // 32768
    int sel = idx >> 14;
    int rem = idx & 16383;
    int i = rem >> 7, j = rem & 127;
    const float2* S = sel ? M64 : Ad;
    float2 v = S[(i & 63)*64 + (j & 63)];
    float o = (i < 64) ? ((j < 64) ? v.x : -v.y)
                       : ((j < 64) ? v.y :  v.x);
    (sel ? ALhat : Ahat)[i*128 + j] = o;
}

// ---------------- big GEMM: Y[M][128] = X1 @ W1^T (+ X2 @ W2^T) ----------------
// X1: [M][K1], W1: [128][K1]. 64x64 tile per wg, 4x4 micro-tile, LDS k-halves.
__global__ __launch_bounds__(256) void gemm_dual(
    const float* __restrict__ X1, int K1, const float* __restrict__ W1,
    const float* __restrict__ X2, int K2v, const float* __restrict__ W2,
    float* __restrict__ Y)
{
    __shared__ float xs_s[64][68];
    __shared__ float ws_s[64][68];
    int t = threadIdx.x;
    int tx = t & 15, ty = t >> 4;
    long row0 = (long)blockIdx.x * 64;
    int  col0 = blockIdx.y * 64;
    float acc[4][4] = {};
    for (int op = 0; op < 2; ++op) {
        const float* X = op ? X2 : X1;
        const float* W = op ? W2 : W1;
        int K = op ? K2v : K1;
        if (X == nullptr) continue;
        for (int kh = 0; kh < K; kh += 64) {
            __syncthreads();
            for (int m = t; m < 64*16; m += 256) {
                int r = m >> 4, cq = m & 15;
                *(float4*)&xs_s[r][cq*4] = *(const float4*)&X[(row0 + r)*K + kh + cq*4];
                *(float4*)&ws_s[r][cq*4] = *(const float4*)&W[(long)(col0 + r)*K + kh + cq*4];
            }
            __syncthreads();
            #pragma unroll
            for (int kq = 0; kq < 16; ++kq) {
                float4 xv[4], wv[4];
                #pragma unroll
                for (int r = 0; r < 4; ++r) xv[r] = *(const float4*)&xs_s[ty + 16*r][kq*4];
                #pragma unroll
                for (int j = 0; j < 4; ++j) wv[j] = *(const float4*)&ws_s[tx + 16*j][kq*4];
                #pragma unroll
                for (int r = 0; r < 4; ++r)
                    #pragma unroll
                    for (int j = 0; j < 4; ++j)
                        acc[r][j] += xv[r].x*wv[j].x + xv[r].y*wv[j].y
                                   + xv[r].z*wv[j].z + xv[r].w*wv[j].w;
            }
        }
    }
    #pragma unroll
    for (int r = 0; r < 4; ++r)
        #pragma unroll
        for (int j = 0; j < 4; ++j)
            Y[(row0 + ty + 16*r)*128 + col0 + tx + 16*j] = acc[r][j];
}

// ---------------- chunked scan passes ----------------
// rows are (b*128 + c), b in [0,32), c chunk in [0,128). 8 rows per wg.
// pass==1: x init 0, write chunk-end to eOut.  pass==3: x init sIn, write Re(x) to xrOut.
// __launch_bounds__(256,1): allow up to 512 VGPRs so av[32] (128 regs) stays
// in registers — R1's (256,2) capped VGPRs at 128 and spilled A to scratch
// (3.4 GB HBM fetch/dispatch, 1.9 ms).
__global__ __launch_bounds__(256, 1) void scan_pass(
    const float* __restrict__ Ahat, const float* __restrict__ bu,
    const float* __restrict__ sIn, float* __restrict__ eOut,
    float* __restrict__ xrOut, int pass)
{
    __shared__ float xs[2][8][132];
    int t = threadIdx.x;
    int i = t & 127, rg = t >> 7, rg4 = rg * 4;
    float4 av[32];
    #pragma unroll
    for (int kq = 0; kq < 32; ++kq)
        av[kq] = *(const float4*)&Ahat[i*128 + kq*4];
    int rowBase = blockIdx.x * 8 + rg4;
    long buOff[4];
    #pragma unroll
    for (int r = 0; r < 4; ++r) {
        int row = rowBase + r;
        long b = row >> 7, c = row & 127;
        buOff[r] = (b * 8192 + c * 64) * 128;
        float v0 = (pass == 3) ? sIn[(long)row*128 + i] : 0.f;
        xs[0][rg4 + r][i] = v0;
    }
    __syncthreads();
    int cur = 0;
    for (int tau = 0; tau < 64; ++tau) {
        float breg[4];
        #pragma unroll
        for (int r = 0; r < 4; ++r) breg[r] = bu[buOff[r] + (long)tau*128 + i];
        float acc[4] = {0.f, 0.f, 0.f, 0.f};
        #pragma unroll
        for (int kq = 0; kq < 32; ++kq) {
            float4 aq = av[kq];
            #pragma unroll
            for (int r = 0; r < 4; ++r) {
                float4 xv = *(const float4*)&xs[cur][rg4 + r][kq*4];
                acc[r] += aq.x*xv.x + aq.y*xv.y + aq.z*xv.z + aq.w*xv.w;
            }
        }
        #pragma unroll
        for (int r = 0; r < 4; ++r) {
            float xn = acc[r] + breg[r];
            xs[cur ^ 1][rg4 + r][i] = xn;
            if (pass == 3 && i < 64) xrOut[(buOff[r] >> 1) + (long)tau*64 + i] = xn;
        }
        __syncthreads();
        cur ^= 1;
    }
    if (pass == 1) {
        #pragma unroll
        for (int r = 0; r < 4; ++r)
            eOut[(long)(rowBase + r)*128 + i] = xs[cur][rg4 + r][i];
    }
}

// phase 2: per batch b, s[c] = ALhat s[c-1] + e[c]; store incoming carry sOut[c] = s[c-1]
__global__ __launch_bounds__(128, 1) void phase2(const float* __restrict__ ALhat,
                                                 const float* __restrict__ eIn,
                                                 float* __restrict__ sOut)
{
    __shared__ float s_s[132];
    int i = threadIdx.x;
    int b = blockIdx.x;
    float4 av[32];
    #pragma unroll
    for (int kq = 0; kq < 32; ++kq)
        av[kq] = *(const float4*)&ALhat[i*128 + kq*4];
    s_s[i] = 0.f;
    __syncthreads();
    for (int c = 0; c < 128; ++c) {
        long row = (long)b*128 + c;
        float e = eIn[row*128 + i];
        sOut[row*128 + i] = s_s[i];          // incoming carry s[c-1]
        float acc = 0.f;
        #pragma unroll
        for (int kq = 0; kq < 32; ++kq) {
            float4 sv = *(const float4*)&s_s[kq*4];
            float4 aq = av[kq];
            acc += aq.x*sv.x + aq.y*sv.y + aq.z*sv.z + aq.w*sv.w;
        }
        __syncthreads();
        s_s[i] = acc + e;
        __syncthreads();
    }
}

// ---------------- launch ----------------

extern "C" void kernel_launch(void* const* d_in, const int* in_sizes, int n_in,
                              void* d_out, int out_size, void* d_ws, size_t ws_size,
                              hipStream_t stream) {
    const float* u  = (const float*)d_in[0];
    const float* lw = (const float*)d_in[1];
    const float* zl = (const float*)d_in[2];
    const float* P  = (const float*)d_in[3];
    const float* Q  = (const float*)d_in[4];
    const float* Bm = (const float*)d_in[5];
    const float* Cm = (const float*)d_in[6];
    const float* Dm = (const float*)d_in[7];
    float* y = (float*)d_out;
    float* w = (float*)d_ws;

    float2* E   = (float2*)(w + OFF_E);
    float2* E2  = (float2*)(w + OFF_E2);
    float2* AD  = (float2*)(w + OFF_AD);
    float2* P0  = (float2*)(w + OFF_P0);
    float2* P1  = (float2*)(w + OFF_P1);
    float*  Ahat  = w + OFF_AHAT;
    float*  ALhat = w + OFF_ALHAT;
    float*  Wbu   = w + OFF_WBU;
    float*  Est   = w + OFF_EST;
    float*  SIn   = w + OFF_SIN;
    float*  XR    = w + OFF_XR;

    // setup
    build_E<<<16, 256, 0, stream>>>(lw, zl, P, Q, E);
    cgemm64<<<4, 256, 0, stream>>>(E, E, E2, 0, 0, 0);        // E^2
    cgemm64<<<4, 256, 0, stream>>>(E, E2, AD, 1, 1, 1);       // A_d = 2(I+E)(I+E^2) - I
    k_bd<<<32, 256, 0, stream>>>(AD, Bm, Wbu);
    cgemm64<<<4, 256, 0, stream>>>(AD, AD, P0, 0, 0, 0);      // A^2
    cgemm64<<<4, 256, 0, stream>>>(P0, P0, P1, 0, 0, 0);      // A^4
    cgemm64<<<4, 256, 0, stream>>>(P1, P1, P0, 0, 0, 0);      // A^8
    cgemm64<<<4, 256, 0, stream>>>(P0, P0, P1, 0, 0, 0);      // A^16
    cgemm64<<<4, 256, 0, stream>>>(P1, P1, P0, 0, 0, 0);      // A^32
    cgemm64<<<4, 256, 0, stream>>>(P0, P0, P1, 0, 0, 0);      // A^64
    k_embed<<<128, 256, 0, stream>>>(AD, P1, Ahat, ALhat);

    // bu = u @ Wbu^T  -> stored in d_out (scratch reuse)
    gemm_dual<<<dim3(4096, 2), 256, 0, stream>>>(u, 128, Wbu, nullptr, 0, nullptr, y);

    // chunked scan
    scan_pass<<<512, 256, 0, stream>>>(Ahat, y, nullptr, Est, nullptr, 1);
    phase2<<<32, 128, 0, stream>>>(ALhat, Est, SIn);
    scan_pass<<<512, 256, 0, stream>>>(Ahat, y, SIn, nullptr, XR, 3);

    // y = xr @ C^T + u @ D^T  (overwrites d_out)
    gemm_dual<<<dim3(4096, 2), 256, 0, stream>>>(XR, 64, Cm, u, 128, Dm, y);
}

// Round 3
// 1059.006 us; speedup vs baseline: 4.4280x; 1.5531x over previous
//
#include <hip/hip_runtime.h>

// OscillatoryDPLRSSM — chunked parallel scan; R3: MFMA-based scan passes.
//
//   E = (dt/2)(diag(lam) + P Q^T);  Minv ~= (I+E)(I+E^2)  (err ~1e-9)
//   A_d = 2*Minv - I;  B_d = 0.05*(A_d+I)*B
//   bu = u @ Wbu^T (fp32 GEMM, stored in d_out)
//   scan: pass1 (zero-init, chunk ends) -> phase2 (128-chain) -> pass3 (seeded, emit Re x)
//   Scan passes use mfma_f32_16x16x32_bf16: X[16,128] <- X + X@DeltaT + BU per step,
//   identity+BU kept fp32 in accumulator; only Delta-product in bf16.
//   y = xr @ C^T + u @ D^T
//
// Workspace layout (floats):
#define OFF_E      0L          // float2[64*64]; reused after setup as DT frags (32 KB)
#define OFF_E2     8192L
#define OFF_AD     16384L
#define OFF_P0     24576L
#define OFF_P1     32768L
#define OFF_AHAT   40960L      // 128*128
#define OFF_ALHAT  57344L
#define OFF_WBU    73728L
#define OFF_EST    90112L      // 4096*128
#define OFF_SIN    614400L     // 4096*128
#define OFF_XR     1138688L    // 262144*64
// total = 17,915,904 floats = 71.7 MB

typedef __attribute__((ext_vector_type(8))) short short8;   // 8 bf16 (4 VGPRs)
typedef __attribute__((ext_vector_type(4))) float f32x4;

union U4S8 { uint4 u; short8 s; };

// ---------------- setup kernels ----------------

__global__ void build_E(const float* __restrict__ lw, const float* __restrict__ zl,
                        const float* __restrict__ P, const float* __restrict__ Q,
                        float2* __restrict__ E)
{
    int idx = blockIdx.x * 256 + threadIdx.x;   // 4096 elements
    if (idx >= 4096) return;
    int i = idx >> 6, j = idx & 63;
    float pq = 0.f;
    #pragma unroll
    for (int r = 0; r < 4; ++r) pq += P[i*4+r] * Q[j*4+r];
    float ex = pq, ey = 0.f;
    if (i == j) {
        float om = expf(lw[i]);
        float ze = 1.f / (1.f + expf(-zl[i]));
        ex += -ze * om;
        ey  = om * sqrtf(fmaxf(1.f - ze*ze, 1e-8f));
    }
    E[idx] = make_float2(0.005f * ex, 0.005f * ey);
}

// Co = (A + aI*I)(B + bI*I); post: Co = 2*Co - I
__global__ __launch_bounds__(256) void cgemm64(const float2* __restrict__ A,
                                               const float2* __restrict__ B,
                                               float2* __restrict__ Co,
                                               int aI, int bI, int post)
{
    int g = blockIdx.x * 256 + threadIdx.x;     // grid 4 -> g in [0,1024)
    #pragma unroll
    for (int q = 0; q < 4; ++q) {
        int idx = g + q * 1024;
        int i = idx >> 6, j = idx & 63;
        float accx = 0.f, accy = 0.f;
        for (int k = 0; k < 64; ++k) {
            float2 a = A[i*64 + k];
            if (aI && k == i) a.x += 1.f;
            float2 b = B[k*64 + j];
            if (bI && k == j) b.x += 1.f;
            accx += a.x*b.x - a.y*b.y;
            accy += a.x*b.y + a.y*b.x;
        }
        if (post) { accx = 2.f*accx - (i == j ? 1.f : 0.f); accy = 2.f*accy; }
        Co[idx] = make_float2(accx, accy);
    }
}

// Wbu (128x128): rows 0..63 = Re(B_d), rows 64..127 = Im(B_d); B_d = 0.05*(A_d+I)*B
__global__ __launch_bounds__(256) void k_bd(const float2* __restrict__ Ad,
                                            const float* __restrict__ Bm,
                                            float* __restrict__ Wbu)
{
    int idx = blockIdx.x * 256 + threadIdx.x;   // 8192
    int n = idx >> 7, i = idx & 127;
    float ar = 0.f, ai = 0.f;
    for (int m = 0; m < 64; ++m) {
        float2 a = Ad[n*64 + m];
        float b = Bm[m*128 + i];
        ar += a.x * b; ai += a.y * b;
    }
    ar += Bm[n*128 + i];                         // +I*B
    Wbu[n*128 + i]      = 0.05f * ar;
    Wbu[(64+n)*128 + i] = 0.05f * ai;
}

// real embedding [[Ar,-Ai],[Ai,Ar]] for A_d and A_d^64
__global__ void k_embed(const float2* __restrict__ Ad, const float2* __restrict__ M64,
                        float* __restrict__ Ahat, float* __restrict__ ALhat)
{
    int idx = blockIdx.x * 256 + threadIdx.x;   // 32768
    int sel = idx >> 14;
    int rem = idx & 16383;
    int i = rem >> 7, j = rem & 127;
    const float2* S = sel ? M64 : Ad;
    float2 v = S[(i & 63)*64 + (j & 63)];
    float o = (i < 64) ? ((j < 64) ? v.x : -v.y)
                       : ((j < 64) ? v.y :  v.x);
    (sel ? ALhat : Ahat)[i*128 + j] = o;
}

// Pre-swizzle DeltaT = (Ahat - I)^T into B-fragment order for mfma_f32_16x16x32_bf16.
// B[k][n]: lane holds n = lane&15, k = (lane>>4)*8 + j (+32*kt). Frag array:
// DTf[(nt*4+kt)*64 + lane][j] bf16, so the scan loads one uint4 per (nt,kt).
__global__ void k_swz(const float* __restrict__ Ahat, ushort* __restrict__ DTf)
{
    int t = blockIdx.x * 256 + threadIdx.x;     // 2048 = 8nt * 4kt * 64lane
    if (t >= 2048) return;
    int lane = t & 63, kt = (t >> 6) & 3, nt = t >> 8;
    int n = (lane & 15) + nt * 16;
    int kbase = (lane >> 4) * 8 + kt * 32;
    #pragma unroll
    for (int j = 0; j < 8; ++j) {
        int k = kbase + j;
        float d = Ahat[n * 128 + k] - (n == k ? 1.f : 0.f);   // B[k][n] = DeltaT[k][n] = Delta[n][k]
        uint u = __float_as_uint(d);
        DTf[t * 8 + j] = (ushort)((u + 0x7FFFu + ((u >> 16) & 1)) >> 16);   // RNE
    }
}

// ---------------- big GEMM: Y[M][128] = X1 @ W1^T (+ X2 @ W2^T) ----------------
__global__ __launch_bounds__(256) void gemm_dual(
    const float* __restrict__ X1, int K1, const float* __restrict__ W1,
    const float* __restrict__ X2, int K2v, const float* __restrict__ W2,
    float* __restrict__ Y)
{
    __shared__ float xs_s[64][68];
    __shared__ float ws_s[64][68];
    int t = threadIdx.x;
    int tx = t & 15, ty = t >> 4;
    long row0 = (long)blockIdx.x * 64;
    int  col0 = blockIdx.y * 64;
    float acc[4][4] = {};
    for (int op = 0; op < 2; ++op) {
        const float* X = op ? X2 : X1;
        const float* W = op ? W2 : W1;
        int K = op ? K2v : K1;
        if (X == nullptr) continue;
        for (int kh = 0; kh < K; kh += 64) {
            __syncthreads();
            for (int m = t; m < 64*16; m += 256) {
                int r = m >> 4, cq = m & 15;
                *(float4*)&xs_s[r][cq*4] = *(const float4*)&X[(row0 + r)*K + kh + cq*4];
                *(float4*)&ws_s[r][cq*4] = *(const float4*)&W[(long)(col0 + r)*K + kh + cq*4];
            }
            __syncthreads();
            #pragma unroll
            for (int kq = 0; kq < 16; ++kq) {
                float4 xv[4], wv[4];
                #pragma unroll
                for (int r = 0; r < 4; ++r) xv[r] = *(const float4*)&xs_s[ty + 16*r][kq*4];
                #pragma unroll
                for (int j = 0; j < 4; ++j) wv[j] = *(const float4*)&ws_s[tx + 16*j][kq*4];
                #pragma unroll
                for (int r = 0; r < 4; ++r)
                    #pragma unroll
                    for (int j = 0; j < 4; ++j)
                        acc[r][j] += xv[r].x*wv[j].x + xv[r].y*wv[j].y
                                   + xv[r].z*wv[j].z + xv[r].w*wv[j].w;
            }
        }
    }
    #pragma unroll
    for (int r = 0; r < 4; ++r)
        #pragma unroll
        for (int j = 0; j < 4; ++j)
            Y[(row0 + ty + 16*r)*128 + col0 + tx + 16*j] = acc[r][j];
}

// ---------------- MFMA scan ----------------
// One wave (block of 64) owns 16 consecutive chunks (same b). Per step:
//   X_new = X_old + X_old @ DeltaT + BU   (identity+BU fp32 in accumulator)
// X D-layout -> A-layout feedback via wave-private LDS (no barriers needed:
// single wave, DS ops in-order). PASS==1: emit chunk ends. PASS==3: seed from
// sIn, emit Re(x) each step.
template <int PASS>
__global__ __launch_bounds__(64, 1) void mfma_scan(
    const uint4* __restrict__ DTf, const float* __restrict__ bu,
    const float* __restrict__ sIn, float* __restrict__ eOut,
    float* __restrict__ xrOut)
{
    __shared__ ushort xlds[16 * 136];    // [chunk m][state], row stride 272 B (16B-aligned)
    int l    = threadIdx.x;
    int col  = l & 15;
    int quad = l >> 4;
    int wid  = blockIdx.x;               // 0..255, 16 chunks each

    // static DeltaT B-frags: 8 ntiles x 4 ktiles (128 VGPRs)
    short8 dtf[8][4];
    #pragma unroll
    for (int nt = 0; nt < 8; ++nt)
        #pragma unroll
        for (int kt = 0; kt < 4; ++kt) {
            U4S8 u; u.u = DTf[(nt*4 + kt)*64 + l];
            dtf[nt][kt] = u.s;
        }

    int  rowg0 = wid * 16;               // global (b*128+c) row of chunk m=0
    long b  = rowg0 >> 7;
    long c0 = rowg0 & 127;

    // accumulator: acc[nt][r] = X[chunk quad*4+r][state col+16*nt]
    f32x4 acc[8];
    #pragma unroll
    for (int nt = 0; nt < 8; ++nt) acc[nt] = (f32x4){0.f, 0.f, 0.f, 0.f};
    if constexpr (PASS == 3) {
        #pragma unroll
        for (int nt = 0; nt < 8; ++nt)
            #pragma unroll
            for (int r = 0; r < 4; ++r)
                acc[nt][r] = sIn[(long)(rowg0 + quad*4 + r)*128 + col + nt*16];
    }

    long buBase[4], xrBase[4];
    #pragma unroll
    for (int r = 0; r < 4; ++r) {
        int m = quad*4 + r;
        long tbase = b*8192 + (c0 + m)*64;
        buBase[r] = tbase*128 + col;
        xrBase[r] = tbase*64 + col;
    }

    float buA[8][4], buB[8][4];
    #define LOADBU(dst, TAU) { long _t = (TAU); _Pragma("unroll") \
        for (int nt = 0; nt < 8; ++nt) { _Pragma("unroll") \
            for (int r = 0; r < 4; ++r) dst[nt][r] = bu[buBase[r] + _t*128 + nt*16]; } }

    auto dostep = [&](float (&bucur)[8][4], int TAU) {
        // WAR fence: previous step's A-frag reads precede these writes (HW: in-order DS)
        asm volatile("" ::: "memory");
        #pragma unroll
        for (int nt = 0; nt < 8; ++nt)
            #pragma unroll
            for (int r = 0; r < 4; ++r) {
                uint u = __float_as_uint(acc[nt][r]);
                xlds[(quad*4 + r)*136 + col + nt*16] = (ushort)((u + 0x8000u) >> 16);
            }
        asm volatile("" ::: "memory");   // RAW fence: writes precede reads
        short8 af[4];
        #pragma unroll
        for (int kt = 0; kt < 4; ++kt) {
            U4S8 u; u.u = *(const uint4*)&xlds[col*136 + quad*8 + kt*32];
            af[kt] = u.s;
        }
        #pragma unroll
        for (int nt = 0; nt < 8; ++nt)
            #pragma unroll
            for (int r = 0; r < 4; ++r) acc[nt][r] += bucur[nt][r];
        #pragma unroll
        for (int kt = 0; kt < 4; ++kt)
            #pragma unroll
            for (int nt = 0; nt < 8; ++nt)
                acc[nt] = __builtin_amdgcn_mfma_f32_16x16x32_bf16(af[kt], dtf[nt][kt], acc[nt], 0, 0, 0);
        if constexpr (PASS == 3) {
            #pragma unroll
            for (int nt = 0; nt < 4; ++nt)       // real half: states 0..63
                #pragma unroll
                for (int r = 0; r < 4; ++r)
                    xrOut[xrBase[r] + (long)TAU*64 + nt*16] = acc[nt][r];
        }
    };

    LOADBU(buA, 0);
    for (int tau = 0; tau < 64; tau += 2) {
        LOADBU(buB, tau + 1);
        dostep(buA, tau);
        LOADBU(buA, (tau + 2 < 64) ? (tau + 2) : 63);   // last is redundant, harmless
        dostep(buB, tau + 1);
    }

    if constexpr (PASS == 1) {
        #pragma unroll
        for (int nt = 0; nt < 8; ++nt)
            #pragma unroll
            for (int r = 0; r < 4; ++r)
                eOut[(long)(rowg0 + quad*4 + r)*128 + col + nt*16] = acc[nt][r];
    }
    #undef LOADBU
}

// phase 2: per batch b, s[c] = ALhat s[c-1] + e[c]; store incoming carry sOut[c] = s[c-1]
__global__ __launch_bounds__(128, 1) void phase2(const float* __restrict__ ALhat,
                                                 const float* __restrict__ eIn,
                                                 float* __restrict__ sOut)
{
    __shared__ float s_s[132];
    int i = threadIdx.x;
    int b = blockIdx.x;
    float4 av[32];
    #pragma unroll
    for (int kq = 0; kq < 32; ++kq)
        av[kq] = *(const float4*)&ALhat[i*128 + kq*4];
    s_s[i] = 0.f;
    __syncthreads();
    for (int c = 0; c < 128; ++c) {
        long row = (long)b*128 + c;
        float e = eIn[row*128 + i];
        sOut[row*128 + i] = s_s[i];          // incoming carry s[c-1]
        float acc = 0.f;
        #pragma unroll
        for (int kq = 0; kq < 32; ++kq) {
            float4 sv = *(const float4*)&s_s[kq*4];
            float4 aq = av[kq];
            acc += aq.x*sv.x + aq.y*sv.y + aq.z*sv.z + aq.w*sv.w;
        }
        __syncthreads();
        s_s[i] = acc + e;
        __syncthreads();
    }
}

// ---------------- launch ----------------

extern "C" void kernel_launch(void* const* d_in, const int* in_sizes, int n_in,
                              void* d_out, int out_size, void* d_ws, size_t ws_size,
                              hipStream_t stream) {
    const float* u  = (const float*)d_in[0];
    const float* lw = (const float*)d_in[1];
    const float* zl = (const float*)d_in[2];
    const float* P  = (const float*)d_in[3];
    const float* Q  = (const float*)d_in[4];
    const float* Bm = (const float*)d_in[5];
    const float* Cm = (const float*)d_in[6];
    const float* Dm = (const float*)d_in[7];
    float* y = (float*)d_out;
    float* w = (float*)d_ws;

    float2* E   = (float2*)(w + OFF_E);
    float2* E2  = (float2*)(w + OFF_E2);
    float2* AD  = (float2*)(w + OFF_AD);
    float2* P0  = (float2*)(w + OFF_P0);
    float2* P1  = (float2*)(w + OFF_P1);
    float*  Ahat  = w + OFF_AHAT;
    float*  ALhat = w + OFF_ALHAT;
    float*  Wbu   = w + OFF_WBU;
    float*  Est   = w + OFF_EST;
    float*  SIn   = w + OFF_SIN;
    float*  XR    = w + OFF_XR;
    ushort* DTf   = (ushort*)(w + OFF_E);    // E region dead after AD computed

    // setup
    build_E<<<16, 256, 0, stream>>>(lw, zl, P, Q, E);
    cgemm64<<<4, 256, 0, stream>>>(E, E, E2, 0, 0, 0);        // E^2
    cgemm64<<<4, 256, 0, stream>>>(E, E2, AD, 1, 1, 1);       // A_d = 2(I+E)(I+E^2) - I
    k_bd<<<32, 256, 0, stream>>>(AD, Bm, Wbu);
    cgemm64<<<4, 256, 0, stream>>>(AD, AD, P0, 0, 0, 0);      // A^2
    cgemm64<<<4, 256, 0, stream>>>(P0, P0, P1, 0, 0, 0);      // A^4
    cgemm64<<<4, 256, 0, stream>>>(P1, P1, P0, 0, 0, 0);      // A^8
    cgemm64<<<4, 256, 0, stream>>>(P0, P0, P1, 0, 0, 0);      // A^16
    cgemm64<<<4, 256, 0, stream>>>(P1, P1, P0, 0, 0, 0);      // A^32
    cgemm64<<<4, 256, 0, stream>>>(P0, P0, P1, 0, 0, 0);      // A^64
    k_embed<<<128, 256, 0, stream>>>(AD, P1, Ahat, ALhat);
    k_swz<<<8, 256, 0, stream>>>(Ahat, DTf);

    // bu = u @ Wbu^T  -> stored in d_out (scratch reuse)
    gemm_dual<<<dim3(4096, 2), 256, 0, stream>>>(u, 128, Wbu, nullptr, 0, nullptr, y);

    // chunked scan (MFMA)
    mfma_scan<1><<<256, 64, 0, stream>>>((const uint4*)DTf, y, nullptr, Est, nullptr);
    phase2<<<32, 128, 0, stream>>>(ALhat, Est, SIn);
    mfma_scan<3><<<256, 64, 0, stream>>>((const uint4*)DTf, y, SIn, nullptr, XR);

    // y = xr @ C^T + u @ D^T  (overwrites d_out)
    gemm_dual<<<dim3(4096, 2), 256, 0, stream>>>(XR, 64, Cm, u, 128, Dm, y);
}